// Round 7
// baseline (220.066 us; speedup 1.0000x reference)
//
#include <hip/hip_runtime.h>

#define HID 64
#define FEAT 10
#define MAXSEG 8192        // fixed per-bucket segment (mean fill 4081, 64 sigma margin)

typedef unsigned short u16;

// ---------- helpers ----------
__device__ __forceinline__ u16 f2bf(float f) {            // fp32 -> bf16 RNE
    unsigned u = __float_as_uint(f);
    unsigned r = (u + 0x7fffu + ((u >> 16) & 1u)) >> 16;
    return (u16)r;
}
__device__ __forceinline__ void bf8_add(float* acc, uint4 u) {
    acc[0] += __uint_as_float(u.x << 16);
    acc[1] += __uint_as_float(u.x & 0xffff0000u);
    acc[2] += __uint_as_float(u.y << 16);
    acc[3] += __uint_as_float(u.y & 0xffff0000u);
    acc[4] += __uint_as_float(u.z << 16);
    acc[5] += __uint_as_float(u.z & 0xffff0000u);
    acc[6] += __uint_as_float(u.w << 16);
    acc[7] += __uint_as_float(u.w & 0xffff0000u);
}

// 2-deep pipelined neighbor gather: two 8-edge groups (16 row-loads) in flight.
// Accumulation order identical to the sequential loop -> bit-identical results.
// RS = row stride in u16 units. acc must hold 8 channels at offset c0.
template<int RS>
__device__ __forceinline__ void gather_rows(float* acc, const u16* __restrict__ base,
                                            const u16* __restrict__ csr2,
                                            int i0, int cnt, int c0) {
    int trips = cnt >> 3;
    if (!trips) return;
    int last = i0 + cnt - 8;
    uint4 evA = *(const uint4*)(csr2 + i0);
    uint4 evB = *(const uint4*)(csr2 + (trips > 1 ? i0 + 8 : i0));
    int j = 0;
    for (; j + 2 <= trips; j += 2) {
        int inA = i0 + 8 * (j + 2); if (inA > last) inA = last;
        int inB = inA + 8;          if (inB > last) inB = last;
        uint4 evA2 = *(const uint4*)(csr2 + inA);
        uint4 evB2 = *(const uint4*)(csr2 + inB);
        uint4 a0 = *(const uint4*)(base + (size_t)(evA.x & 0xffff) * RS + c0);
        uint4 a1 = *(const uint4*)(base + (size_t)(evA.x >> 16)    * RS + c0);
        uint4 a2 = *(const uint4*)(base + (size_t)(evA.y & 0xffff) * RS + c0);
        uint4 a3 = *(const uint4*)(base + (size_t)(evA.y >> 16)    * RS + c0);
        uint4 a4 = *(const uint4*)(base + (size_t)(evA.z & 0xffff) * RS + c0);
        uint4 a5 = *(const uint4*)(base + (size_t)(evA.z >> 16)    * RS + c0);
        uint4 a6 = *(const uint4*)(base + (size_t)(evA.w & 0xffff) * RS + c0);
        uint4 a7 = *(const uint4*)(base + (size_t)(evA.w >> 16)    * RS + c0);
        uint4 b0 = *(const uint4*)(base + (size_t)(evB.x & 0xffff) * RS + c0);
        uint4 b1 = *(const uint4*)(base + (size_t)(evB.x >> 16)    * RS + c0);
        uint4 b2 = *(const uint4*)(base + (size_t)(evB.y & 0xffff) * RS + c0);
        uint4 b3 = *(const uint4*)(base + (size_t)(evB.y >> 16)    * RS + c0);
        uint4 b4 = *(const uint4*)(base + (size_t)(evB.z & 0xffff) * RS + c0);
        uint4 b5 = *(const uint4*)(base + (size_t)(evB.z >> 16)    * RS + c0);
        uint4 b6 = *(const uint4*)(base + (size_t)(evB.w & 0xffff) * RS + c0);
        uint4 b7 = *(const uint4*)(base + (size_t)(evB.w >> 16)    * RS + c0);
        bf8_add(acc, a0); bf8_add(acc, a1); bf8_add(acc, a2); bf8_add(acc, a3);
        bf8_add(acc, a4); bf8_add(acc, a5); bf8_add(acc, a6); bf8_add(acc, a7);
        bf8_add(acc, b0); bf8_add(acc, b1); bf8_add(acc, b2); bf8_add(acc, b3);
        bf8_add(acc, b4); bf8_add(acc, b5); bf8_add(acc, b6); bf8_add(acc, b7);
        evA = evA2; evB = evB2;
    }
    if (j < trips) {                       // final odd group (ev already resident)
        uint4 a0 = *(const uint4*)(base + (size_t)(evA.x & 0xffff) * RS + c0);
        uint4 a1 = *(const uint4*)(base + (size_t)(evA.x >> 16)    * RS + c0);
        uint4 a2 = *(const uint4*)(base + (size_t)(evA.y & 0xffff) * RS + c0);
        uint4 a3 = *(const uint4*)(base + (size_t)(evA.y >> 16)    * RS + c0);
        uint4 a4 = *(const uint4*)(base + (size_t)(evA.z & 0xffff) * RS + c0);
        uint4 a5 = *(const uint4*)(base + (size_t)(evA.z >> 16)    * RS + c0);
        uint4 a6 = *(const uint4*)(base + (size_t)(evA.w & 0xffff) * RS + c0);
        uint4 a7 = *(const uint4*)(base + (size_t)(evA.w >> 16)    * RS + c0);
        bf8_add(acc, a0); bf8_add(acc, a1); bf8_add(acc, a2); bf8_add(acc, a3);
        bf8_add(acc, a4); bf8_add(acc, a5); bf8_add(acc, a6); bf8_add(acc, a7);
    }
}

// ================= CSR build (2 kernels) =================

// One pass over edges: LDS histogram -> global range reservation -> emit from registers.
// Bucket b owns tmp[b*MAXSEG .. b*MAXSEG+cnt). Also zeroes sentinel rows (block 0).
__global__ __launch_bounds__(1024) void bin_kernel(
        const int* __restrict__ src, const int* __restrict__ dst,
        int* __restrict__ gcnt, unsigned* __restrict__ tmp,
        u16* __restrict__ hwba, u16* __restrict__ hwbb, u16* __restrict__ xp,
        int E, int N) {
    __shared__ int h[256];           // histogram, then current-slot cursors
    int t = threadIdx.x, c = blockIdx.x;
    if (t < 256) h[t] = 0;
    __syncthreads();
    int b0 = c * 4096;
    unsigned pk[4]; int bk[4];
    #pragma unroll
    for (int j = 0; j < 4; j++) {
        int e = b0 + t + j * 1024;
        if (e < E) {
            int s = src[e], d = dst[e];
            pk[j] = ((unsigned)(d & 255) << 16) | (unsigned)s;
            bk[j] = d >> 8;
            atomicAdd(&h[bk[j]], 1);
        } else bk[j] = -1;
    }
    __syncthreads();
    if (t < 256) {
        int v = h[t];
        int resv = v ? atomicAdd(&gcnt[t], v) : 0;
        h[t] = t * MAXSEG + resv;    // cursor = fixed bucket base + reserved offset
    }
    __syncthreads();
    #pragma unroll
    for (int j = 0; j < 4; j++) {
        if (bk[j] >= 0) {
            int slot = atomicAdd(&h[bk[j]], 1);
            tmp[slot] = pk[j];
        }
    }
    if (c == 0) {                    // sentinel rows (node N): zero
        if (t < 64)       hwba[(size_t)N * 64 + t] = 0;
        else if (t < 128) hwbb[(size_t)N * 64 + (t - 64)] = 0;
        else if (t < 144) xp[(size_t)N * 16 + (t - 128)] = 0;
    }
}

// per-bucket node-sort into padded u16 CSR + row metadata + dinv + pad_x
__global__ __launch_bounds__(1024) void csr_build(
        const unsigned* __restrict__ tmp, const int* __restrict__ gcnt,
        u16* __restrict__ csr2,
        int* __restrict__ row_start, int* __restrict__ row_cntp,
        float* __restrict__ dinv,
        const float* __restrict__ x, u16* __restrict__ xp, int N) {
    __shared__ __align__(16) u16 staged[MAXSEG];
    __shared__ int cntL[256], padL[256], scanL[256], curL[256];
    __shared__ float sdinv[256];
    int b = blockIdx.x, t = threadIdx.x;          // 1024 threads
    if (t < 256) cntL[t] = 0;
    for (int i = t; i < MAXSEG; i += 1024) staged[i] = (u16)N;   // sentinel prefill
    __syncthreads();
    int segBase = b * MAXSEG, segLen = gcnt[b];
    for (int i = t; i < segLen; i += 1024)
        atomicAdd(&cntL[tmp[segBase + i] >> 16], 1);
    __syncthreads();
    if (t < 256) { padL[t] = (cntL[t] + 7) & ~7; scanL[t] = padL[t]; }
    __syncthreads();
    for (int off = 1; off < 256; off <<= 1) {
        int a = (t < 256) ? scanL[t] : 0;
        int s = (t >= off && t < 256) ? scanL[t - off] : 0;
        __syncthreads();
        if (t < 256) scanL[t] = a + s;
        __syncthreads();
    }
    if (t < 256) {
        int excl = scanL[t] - padL[t];
        curL[t] = excl;
        float dv = rsqrtf((float)cntL[t] + 1.0f);
        sdinv[t] = dv;
        int node = b * 256 + t;
        if (node < N) {
            row_start[node] = b * MAXSEG + excl;
            row_cntp[node]  = padL[t];
            dinv[node]      = dv;
        }
    }
    __syncthreads();
    for (int i = t; i < segLen; i += 1024) {
        unsigned e = tmp[segBase + i];
        int idx = atomicAdd(&curL[e >> 16], 1);
        staged[idx] = (u16)(e & 0xffffu);
    }
    // pad_x for this bucket's 256 nodes (independent of staged[])
    for (int i = t; i < 256 * 16; i += 1024) {
        int nlc = i >> 4, cch = i & 15;
        int node = b * 256 + nlc;
        if (node < N)
            xp[(size_t)node * 16 + cch] =
                (cch < FEAT) ? f2bf(sdinv[nlc] * x[(size_t)node * FEAT + cch]) : (u16)0;
    }
    __syncthreads();
    ((uint4*)(csr2 + (size_t)b * MAXSEG))[t] = ((const uint4*)staged)[t];
}

// ================= fused layer1 (gather_x+mm1) + layer2-matmul (W2) =================
// 256 threads, 64 nodes per block. h1 never leaves LDS.

__global__ __launch_bounds__(256) void l1l2(
        const int* __restrict__ row_start, const int* __restrict__ row_cntp,
        const u16* __restrict__ csr2, const u16* __restrict__ xp,
        const float* __restrict__ dinv,
        const float* __restrict__ W1, const float* __restrict__ b1,
        const float* __restrict__ W2,
        u16* __restrict__ hwba, int N) {
    __shared__ float sW[64 * 64];        // W1 (first 640) then W2
    __shared__ float sH16[64 * 16];      // scaled aggregate of x
    __shared__ float sH64[64 * 65];      // h1
    int t = threadIdx.x;
    int node0 = blockIdx.x * 64;
    for (int i = t; i < FEAT * 64; i += 256) sW[i] = W1[i];
    if (t < 128) {
        int nl = t >> 1;
        int node = node0 + nl;
        int c0 = (t & 1) * 8;
        float acc[8] = {0.f,0.f,0.f,0.f,0.f,0.f,0.f,0.f};
        if (node < N) {
            uint4 sv = *(const uint4*)(xp + (size_t)node * 16 + c0);
            bf8_add(acc, sv);
            gather_rows<16>(acc, xp, csr2, row_start[node], row_cntp[node], c0);
            float di = dinv[node];
            #pragma unroll
            for (int j = 0; j < 8; j++) acc[j] *= di;
        }
        #pragma unroll
        for (int j = 0; j < 8; j++) sH16[nl * 16 + c0 + j] = acc[j];
    }
    __syncthreads();
    // mm1: h1 = relu(agg @ W1 + b1) -> sH64
    int c0 = (t & 15) * 4;
    int rbase = (t >> 4) * 4;
    {
        float4 a0 = {0,0,0,0}, a1 = {0,0,0,0}, a2 = {0,0,0,0}, a3 = {0,0,0,0};
        for (int k = 0; k < FEAT; k++) {
            float4 w = *(const float4*)(sW + k * 64 + c0);
            float h0 = sH16[(rbase + 0) * 16 + k];
            float h1v = sH16[(rbase + 1) * 16 + k];
            float h2 = sH16[(rbase + 2) * 16 + k];
            float h3 = sH16[(rbase + 3) * 16 + k];
            a0.x += h0 * w.x; a0.y += h0 * w.y; a0.z += h0 * w.z; a0.w += h0 * w.w;
            a1.x += h1v * w.x; a1.y += h1v * w.y; a1.z += h1v * w.z; a1.w += h1v * w.w;
            a2.x += h2 * w.x; a2.y += h2 * w.y; a2.z += h2 * w.z; a2.w += h2 * w.w;
            a3.x += h3 * w.x; a3.y += h3 * w.y; a3.z += h3 * w.z; a3.w += h3 * w.w;
        }
        float4 bb = *(const float4*)(b1 + c0);
        float4 accs[4] = {a0, a1, a2, a3};
        #pragma unroll
        for (int rr = 0; rr < 4; rr++) {
            float4 v = accs[rr];
            int r = rbase + rr;
            sH64[r * 65 + c0 + 0] = fmaxf(v.x + bb.x, 0.f);
            sH64[r * 65 + c0 + 1] = fmaxf(v.y + bb.y, 0.f);
            sH64[r * 65 + c0 + 2] = fmaxf(v.z + bb.z, 0.f);
            sH64[r * 65 + c0 + 3] = fmaxf(v.w + bb.w, 0.f);
        }
    }
    __syncthreads();                 // mm1 done reading sW(W1)
    for (int i = t * 4; i < 4096; i += 256 * 4)
        *(float4*)(sW + i) = *(const float4*)(W2 + i);
    __syncthreads();
    // mm64: hwba = bf16(dinv * (h1 @ W2))
    {
        float4 a0 = {0,0,0,0}, a1 = {0,0,0,0}, a2 = {0,0,0,0}, a3 = {0,0,0,0};
        for (int k = 0; k < 64; k++) {
            float4 w = *(const float4*)(sW + k * 64 + c0);
            float h0 = sH64[(rbase + 0) * 65 + k];
            float h1v = sH64[(rbase + 1) * 65 + k];
            float h2 = sH64[(rbase + 2) * 65 + k];
            float h3 = sH64[(rbase + 3) * 65 + k];
            a0.x += h0 * w.x; a0.y += h0 * w.y; a0.z += h0 * w.z; a0.w += h0 * w.w;
            a1.x += h1v * w.x; a1.y += h1v * w.y; a1.z += h1v * w.z; a1.w += h1v * w.w;
            a2.x += h2 * w.x; a2.y += h2 * w.y; a2.z += h2 * w.z; a2.w += h2 * w.w;
            a3.x += h3 * w.x; a3.y += h3 * w.y; a3.z += h3 * w.z; a3.w += h3 * w.w;
        }
        float4 accs[4] = {a0, a1, a2, a3};
        for (int rr = 0; rr < 4; rr++) {
            int node = node0 + rbase + rr;
            if (node >= N) break;
            float di = dinv[node];
            float4 v = accs[rr];
            ushort4 o;
            o.x = f2bf(v.x * di); o.y = f2bf(v.y * di);
            o.z = f2bf(v.z * di); o.w = f2bf(v.w * di);
            *(ushort4*)(hwba + (size_t)node * 64 + c0) = o;
        }
    }
}

// ================= fused layer2-gather (b2) + layer3-matmul (W3) =================
// 512 threads, 64 nodes per block. h2 never leaves LDS. Reads hwba, writes hwbb.

__global__ __launch_bounds__(512) void g2l3(
        const int* __restrict__ row_start, const int* __restrict__ row_cntp,
        const u16* __restrict__ csr2, const u16* __restrict__ hwba,
        const float* __restrict__ dinv, const float* __restrict__ b2,
        const float* __restrict__ W3,
        u16* __restrict__ hwbb, int N) {
    __shared__ float sW[64 * 64];
    __shared__ float sH64[64 * 65];      // h2
    int t = threadIdx.x;
    int node0 = blockIdx.x * 64;
    {
        int nl = t >> 3;                 // 0..63 node slot
        int node = node0 + nl;
        int c0 = (t & 7) * 8;            // this lane's 8 channels
        float acc[8] = {0.f,0.f,0.f,0.f,0.f,0.f,0.f,0.f};
        if (node < N) {
            uint4 sv = *(const uint4*)(hwba + (size_t)node * 64 + c0);
            bf8_add(acc, sv);
            gather_rows<64>(acc, hwba, csr2, row_start[node], row_cntp[node], c0);
            float di = dinv[node];
            const float4 bb0 = *(const float4*)(b2 + c0);
            const float4 bb1 = *(const float4*)(b2 + c0 + 4);
            acc[0] = fmaxf(acc[0]*di + bb0.x, 0.f); acc[1] = fmaxf(acc[1]*di + bb0.y, 0.f);
            acc[2] = fmaxf(acc[2]*di + bb0.z, 0.f); acc[3] = fmaxf(acc[3]*di + bb0.w, 0.f);
            acc[4] = fmaxf(acc[4]*di + bb1.x, 0.f); acc[5] = fmaxf(acc[5]*di + bb1.y, 0.f);
            acc[6] = fmaxf(acc[6]*di + bb1.z, 0.f); acc[7] = fmaxf(acc[7]*di + bb1.w, 0.f);
        }
        #pragma unroll
        for (int j = 0; j < 8; j++) sH64[nl * 65 + c0 + j] = acc[j];
    }
    for (int i = t * 4; i < 4096; i += 512 * 4)
        *(float4*)(sW + i) = *(const float4*)(W3 + i);
    __syncthreads();
    // mm64: hwbb = bf16(dinv * (h2 @ W3)); 512 threads -> 2 rows x 4 cols each
    {
        int c0 = (t & 15) * 4;
        int r0 = (t >> 4) * 2;
        float4 a0 = {0,0,0,0}, a1 = {0,0,0,0};
        for (int k = 0; k < 64; k++) {
            float4 w = *(const float4*)(sW + k * 64 + c0);
            float h0 = sH64[(r0 + 0) * 65 + k];
            float h1v = sH64[(r0 + 1) * 65 + k];
            a0.x += h0 * w.x; a0.y += h0 * w.y; a0.z += h0 * w.z; a0.w += h0 * w.w;
            a1.x += h1v * w.x; a1.y += h1v * w.y; a1.z += h1v * w.z; a1.w += h1v * w.w;
        }
        float4 accs[2] = {a0, a1};
        for (int rr = 0; rr < 2; rr++) {
            int node = node0 + r0 + rr;
            if (node >= N) break;
            float di = dinv[node];
            float4 v = accs[rr];
            ushort4 o;
            o.x = f2bf(v.x * di); o.y = f2bf(v.y * di);
            o.z = f2bf(v.z * di); o.w = f2bf(v.w * di);
            *(ushort4*)(hwbb + (size_t)node * 64 + c0) = o;
        }
    }
}

// ================= layer3 gather (b3) -> h3 + per-block partial sums =================

__global__ __launch_bounds__(256) void gather_b3(
        const int* __restrict__ row_start, const int* __restrict__ row_cntp,
        const u16* __restrict__ csr2, const u16* __restrict__ hwbb,
        const float* __restrict__ dinv, const float* __restrict__ b,
        float* __restrict__ out, float* __restrict__ part, int N) {
    int t = threadIdx.x;
    int nl = t >> 3;                       // 0..31 node slot in block
    int node = blockIdx.x * 32 + nl;
    int c0 = (t & 7) * 8;
    float acc[8] = {0.f,0.f,0.f,0.f,0.f,0.f,0.f,0.f};
    if (node < N) {
        uint4 sv = *(const uint4*)(hwbb + (size_t)node * 64 + c0);
        bf8_add(acc, sv);
        gather_rows<64>(acc, hwbb, csr2, row_start[node], row_cntp[node], c0);
        float di = dinv[node];
        const float4 bb0 = *(const float4*)(b + c0);
        const float4 bb1 = *(const float4*)(b + c0 + 4);
        float4 o0, o1;
        o0.x = fmaxf(acc[0]*di + bb0.x, 0.f); o0.y = fmaxf(acc[1]*di + bb0.y, 0.f);
        o0.z = fmaxf(acc[2]*di + bb0.z, 0.f); o0.w = fmaxf(acc[3]*di + bb0.w, 0.f);
        o1.x = fmaxf(acc[4]*di + bb1.x, 0.f); o1.y = fmaxf(acc[5]*di + bb1.y, 0.f);
        o1.z = fmaxf(acc[6]*di + bb1.z, 0.f); o1.w = fmaxf(acc[7]*di + bb1.w, 0.f);
        *(float4*)(out + (size_t)node * 64 + c0)     = o0;
        *(float4*)(out + (size_t)node * 64 + c0 + 4) = o1;
        acc[0]=o0.x; acc[1]=o0.y; acc[2]=o0.z; acc[3]=o0.w;
        acc[4]=o1.x; acc[5]=o1.y; acc[6]=o1.z; acc[7]=o1.w;
    }
    __shared__ float red[32 * 64];
    #pragma unroll
    for (int j = 0; j < 8; j++) red[nl * 64 + c0 + j] = acc[j];
    __syncthreads();
    if (t < 64) {
        float s = 0.f;
        #pragma unroll 8
        for (int k = 0; k < 32; k++) s += red[k * 64 + t];
        part[(size_t)blockIdx.x * 64 + t] = s;    // plain store, no device-scope atomic storm
    }
}

// reduce 1563x64 block partials -> gsum[64]. One wave per channel.
__global__ __launch_bounds__(64) void gsum_reduce(const float* __restrict__ part,
                                                  float* __restrict__ gsum, int NB) {
    int c = blockIdx.x, t = threadIdx.x;
    float s = 0.f;
    for (int i = t; i < NB; i += 64) s += part[(size_t)i * 64 + c];
    for (int off = 32; off > 0; off >>= 1) s += __shfl_down(s, off, 64);
    if (t == 0) gsum[c] = s;
}

// ================= head =================

__global__ __launch_bounds__(256) void final_kernel(
        const float* __restrict__ h3, const int* __restrict__ sheet_idx,
        const float* __restrict__ sheet_feat, const float* __restrict__ g_sum,
        const float* __restrict__ gW1, const float* __restrict__ gb1,
        const float* __restrict__ gW2, const float* __restrict__ gb2,
        const float* __restrict__ fW,  const float* __restrict__ fb,
        const float* __restrict__ qW1, const float* __restrict__ qb1,
        const float* __restrict__ qW2, const float* __restrict__ qb2,
        float* __restrict__ out, int N, int L) {
    int s = blockIdx.x, t = threadIdx.x;
    __shared__ float red[256];
    __shared__ float semb[64];
    __shared__ float geoh[64];
    __shared__ float geo[64];
    __shared__ float hq[128];
    int c = t & 63, jg = t >> 6;
    float acc = 0.0f;
    for (int j = jg; j < L; j += 4) {
        int node = sheet_idx[s * L + j];
        acc += h3[(size_t)node * 64 + c];
    }
    red[t] = acc;
    __syncthreads();
    if (t < 64) {
        semb[t] = (red[t] + red[t + 64] + red[t + 128] + red[t + 192]) / (float)L;
        hq[64 + t] = g_sum[t] / (float)N;
        float a = gb1[t];
        #pragma unroll
        for (int k = 0; k < FEAT; k++) a += sheet_feat[s * FEAT + k] * gW1[k * 64 + t];
        geoh[t] = fmaxf(a, 0.0f);
    }
    __syncthreads();
    if (t < 64) {
        float a = gb2[t];
        for (int k = 0; k < 64; k++) a += geoh[k] * gW2[k * 64 + t];
        geo[t] = a;
    }
    __syncthreads();
    if (t < 64) {
        float a = fb[t];
        for (int k = 0; k < 64; k++) a += semb[k] * fW[k * 64 + t];
        for (int k = 0; k < 64; k++) a += geo[k]  * fW[(64 + k) * 64 + t];
        hq[t] = fmaxf(a, 0.0f);
    }
    __syncthreads();
    float q = 0.0f;
    if (t < 64) {
        float a = qb1[t];
        for (int k = 0; k < 128; k++) a += hq[k] * qW1[k * 64 + t];
        a = fmaxf(a, 0.0f);
        q = a * qW2[t];
        for (int off = 32; off > 0; off >>= 1) q += __shfl_down(q, off, 64);
        if (t == 0) out[s] = q + qb2[0];
    }
}

extern "C" void kernel_launch(void* const* d_in, const int* in_sizes, int n_in,
                              void* d_out, int out_size, void* d_ws, size_t ws_size,
                              hipStream_t stream) {
    const float* x          = (const float*)d_in[0];
    const int*   edge       = (const int*)d_in[1];
    const int*   sheet_idx  = (const int*)d_in[3];
    const float* sheet_feat = (const float*)d_in[4];
    const float* W1 = (const float*)d_in[5];  const float* b1 = (const float*)d_in[6];
    const float* W2 = (const float*)d_in[7];  const float* b2 = (const float*)d_in[8];
    const float* W3 = (const float*)d_in[9];  const float* b3 = (const float*)d_in[10];
    const float* gW1 = (const float*)d_in[11]; const float* gb1 = (const float*)d_in[12];
    const float* gW2 = (const float*)d_in[13]; const float* gb2 = (const float*)d_in[14];
    const float* fW  = (const float*)d_in[15]; const float* fb  = (const float*)d_in[16];
    const float* qW1 = (const float*)d_in[17]; const float* qb1 = (const float*)d_in[18];
    const float* qW2 = (const float*)d_in[19]; const float* qb2 = (const float*)d_in[20];
    float* out = (float*)d_out;

    int N = in_sizes[2];            // 50000
    int E = in_sizes[1] / 2;        // 800000
    int S = in_sizes[4] / FEAT;     // 256
    int L = in_sizes[3] / S;        // 128

    int nbuckets = (N + 255) / 256;     // 196 (u16 src requires N < 65535)
    int nchunks  = (E + 4095) / 4096;   // 196

    int gMM = (N + 63) / 64;            // 782
    int gGB = (N + 31) / 32;            // 1563

    char* p = (char*)d_ws;
    unsigned* tmp  = (unsigned*)p;             p += (size_t)nbuckets * MAXSEG * 4;
    u16* csr2      = (u16*)p;                  p += (size_t)nbuckets * MAXSEG * 2;
    float* hf      = (float*)p;                p += (size_t)N * 64 * 4;      // h3 only
    u16* hwba      = (u16*)p;                  p += (size_t)(N + 1) * 64 * 2; // layer2 matmul out
    u16* hwbb      = (u16*)p;                  p += (size_t)(N + 1) * 64 * 2; // layer3 matmul out
    u16* xp        = (u16*)p;                  p += (size_t)(N + 1) * 16 * 2;
    int* row_start = (int*)p;                  p += (size_t)N * 4;
    int* row_cntp  = (int*)p;                  p += (size_t)N * 4;
    float* dinv    = (float*)p;                p += (size_t)N * 4;
    float* part    = (float*)p;                p += (size_t)gGB * 64 * 4;    // block partials
    int* gcnt      = (int*)p;                  p += 256 * 4;
    float* gsum    = (float*)p;                p += 64 * 4;

    hipMemsetAsync(gcnt, 0, 256 * 4, stream);   // gcnt only (gsum overwritten by reduce)

    const int* src = edge;
    const int* dst = edge + E;

    bin_kernel<<<nchunks, 1024, 0, stream>>>(src, dst, gcnt, tmp, hwba, hwbb, xp, E, N);
    csr_build<<<nbuckets, 1024, 0, stream>>>(tmp, gcnt, csr2, row_start, row_cntp, dinv, x, xp, N);

    l1l2<<<gMM, 256, 0, stream>>>(row_start, row_cntp, csr2, xp, dinv, W1, b1, W2, hwba, N);
    g2l3<<<gMM, 512, 0, stream>>>(row_start, row_cntp, csr2, hwba, dinv, b2, W3, hwbb, N);
    gather_b3<<<gGB, 256, 0, stream>>>(row_start, row_cntp, csr2, hwbb, dinv, b3, hf, part, N);
    gsum_reduce<<<64, 64, 0, stream>>>(part, gsum, gGB);

    final_kernel<<<S, 256, 0, stream>>>(hf, sheet_idx, sheet_feat, gsum,
                                        gW1, gb1, gW2, gb2, fW, fb,
                                        qW1, qb1, qW2, qb2, out, N, L);
}

// Round 8
// 193.569 us; speedup vs baseline: 1.1369x; 1.1369x over previous
//
#include <hip/hip_runtime.h>

#define HID 64
#define FEAT 10
#define MAXSEG 8192        // fixed per-bucket segment (mean fill 4081, 64 sigma margin)
#define HSTR 72            // bf16 LDS row stride (64 + 8 pad)

typedef unsigned short u16;
typedef __attribute__((ext_vector_type(8))) short bf16x8;   // 8 bf16 = 4 VGPR (MFMA A/B frag)
typedef __attribute__((ext_vector_type(4))) float f32x4;    // MFMA C/D frag

// ---------- helpers ----------
__device__ __forceinline__ u16 f2bf(float f) {            // fp32 -> bf16 RNE
    unsigned u = __float_as_uint(f);
    unsigned r = (u + 0x7fffu + ((u >> 16) & 1u)) >> 16;
    return (u16)r;
}
__device__ __forceinline__ void bf8_add(float* acc, uint4 u) {
    acc[0] += __uint_as_float(u.x << 16);
    acc[1] += __uint_as_float(u.x & 0xffff0000u);
    acc[2] += __uint_as_float(u.y << 16);
    acc[3] += __uint_as_float(u.y & 0xffff0000u);
    acc[4] += __uint_as_float(u.z << 16);
    acc[5] += __uint_as_float(u.z & 0xffff0000u);
    acc[6] += __uint_as_float(u.w << 16);
    acc[7] += __uint_as_float(u.w & 0xffff0000u);
}

// 2-deep pipelined neighbor gather (bit-identical accumulation order).
template<int RS>
__device__ __forceinline__ void gather_rows(float* acc, const u16* __restrict__ base,
                                            const u16* __restrict__ csr2,
                                            int i0, int cnt, int c0) {
    int trips = cnt >> 3;
    if (!trips) return;
    int last = i0 + cnt - 8;
    uint4 evA = *(const uint4*)(csr2 + i0);
    uint4 evB = *(const uint4*)(csr2 + (trips > 1 ? i0 + 8 : i0));
    int j = 0;
    for (; j + 2 <= trips; j += 2) {
        int inA = i0 + 8 * (j + 2); if (inA > last) inA = last;
        int inB = inA + 8;          if (inB > last) inB = last;
        uint4 evA2 = *(const uint4*)(csr2 + inA);
        uint4 evB2 = *(const uint4*)(csr2 + inB);
        uint4 a0 = *(const uint4*)(base + (size_t)(evA.x & 0xffff) * RS + c0);
        uint4 a1 = *(const uint4*)(base + (size_t)(evA.x >> 16)    * RS + c0);
        uint4 a2 = *(const uint4*)(base + (size_t)(evA.y & 0xffff) * RS + c0);
        uint4 a3 = *(const uint4*)(base + (size_t)(evA.y >> 16)    * RS + c0);
        uint4 a4 = *(const uint4*)(base + (size_t)(evA.z & 0xffff) * RS + c0);
        uint4 a5 = *(const uint4*)(base + (size_t)(evA.z >> 16)    * RS + c0);
        uint4 a6 = *(const uint4*)(base + (size_t)(evA.w & 0xffff) * RS + c0);
        uint4 a7 = *(const uint4*)(base + (size_t)(evA.w >> 16)    * RS + c0);
        uint4 b0 = *(const uint4*)(base + (size_t)(evB.x & 0xffff) * RS + c0);
        uint4 b1 = *(const uint4*)(base + (size_t)(evB.x >> 16)    * RS + c0);
        uint4 b2 = *(const uint4*)(base + (size_t)(evB.y & 0xffff) * RS + c0);
        uint4 b3 = *(const uint4*)(base + (size_t)(evB.y >> 16)    * RS + c0);
        uint4 b4 = *(const uint4*)(base + (size_t)(evB.z & 0xffff) * RS + c0);
        uint4 b5 = *(const uint4*)(base + (size_t)(evB.z >> 16)    * RS + c0);
        uint4 b6 = *(const uint4*)(base + (size_t)(evB.w & 0xffff) * RS + c0);
        uint4 b7 = *(const uint4*)(base + (size_t)(evB.w >> 16)    * RS + c0);
        bf8_add(acc, a0); bf8_add(acc, a1); bf8_add(acc, a2); bf8_add(acc, a3);
        bf8_add(acc, a4); bf8_add(acc, a5); bf8_add(acc, a6); bf8_add(acc, a7);
        bf8_add(acc, b0); bf8_add(acc, b1); bf8_add(acc, b2); bf8_add(acc, b3);
        bf8_add(acc, b4); bf8_add(acc, b5); bf8_add(acc, b6); bf8_add(acc, b7);
        evA = evA2; evB = evB2;
    }
    if (j < trips) {
        uint4 a0 = *(const uint4*)(base + (size_t)(evA.x & 0xffff) * RS + c0);
        uint4 a1 = *(const uint4*)(base + (size_t)(evA.x >> 16)    * RS + c0);
        uint4 a2 = *(const uint4*)(base + (size_t)(evA.y & 0xffff) * RS + c0);
        uint4 a3 = *(const uint4*)(base + (size_t)(evA.y >> 16)    * RS + c0);
        uint4 a4 = *(const uint4*)(base + (size_t)(evA.z & 0xffff) * RS + c0);
        uint4 a5 = *(const uint4*)(base + (size_t)(evA.z >> 16)    * RS + c0);
        uint4 a6 = *(const uint4*)(base + (size_t)(evA.w & 0xffff) * RS + c0);
        uint4 a7 = *(const uint4*)(base + (size_t)(evA.w >> 16)    * RS + c0);
        bf8_add(acc, a0); bf8_add(acc, a1); bf8_add(acc, a2); bf8_add(acc, a3);
        bf8_add(acc, a4); bf8_add(acc, a5); bf8_add(acc, a6); bf8_add(acc, a7);
    }
}

// ================= CSR build (2 kernels) =================

__global__ __launch_bounds__(1024) void bin_kernel(
        const int* __restrict__ src, const int* __restrict__ dst,
        int* __restrict__ gcnt, unsigned* __restrict__ tmp,
        u16* __restrict__ hwba, u16* __restrict__ hwbb, u16* __restrict__ xp,
        int E, int N) {
    __shared__ int h[256];
    int t = threadIdx.x, c = blockIdx.x;
    if (t < 256) h[t] = 0;
    __syncthreads();
    int b0 = c * 4096;
    unsigned pk[4]; int bk[4];
    #pragma unroll
    for (int j = 0; j < 4; j++) {
        int e = b0 + t + j * 1024;
        if (e < E) {
            int s = src[e], d = dst[e];
            pk[j] = ((unsigned)(d & 255) << 16) | (unsigned)s;
            bk[j] = d >> 8;
            atomicAdd(&h[bk[j]], 1);
        } else bk[j] = -1;
    }
    __syncthreads();
    if (t < 256) {
        int v = h[t];
        int resv = v ? atomicAdd(&gcnt[t], v) : 0;
        h[t] = t * MAXSEG + resv;
    }
    __syncthreads();
    #pragma unroll
    for (int j = 0; j < 4; j++) {
        if (bk[j] >= 0) {
            int slot = atomicAdd(&h[bk[j]], 1);
            tmp[slot] = pk[j];
        }
    }
    if (c == 0) {                    // sentinel rows (node N): zero
        if (t < 64)       hwba[(size_t)N * 64 + t] = 0;
        else if (t < 128) hwbb[(size_t)N * 64 + (t - 64)] = 0;
        else if (t < 144) xp[(size_t)N * 16 + (t - 128)] = 0;
    }
}

__global__ __launch_bounds__(1024) void csr_build(
        const unsigned* __restrict__ tmp, const int* __restrict__ gcnt,
        u16* __restrict__ csr2,
        int* __restrict__ row_start, int* __restrict__ row_cntp,
        float* __restrict__ dinv,
        const float* __restrict__ x, u16* __restrict__ xp, int N) {
    __shared__ __align__(16) u16 staged[MAXSEG];
    __shared__ int cntL[256], padL[256], scanL[256], curL[256];
    __shared__ float sdinv[256];
    int b = blockIdx.x, t = threadIdx.x;
    if (t < 256) cntL[t] = 0;
    for (int i = t; i < MAXSEG; i += 1024) staged[i] = (u16)N;
    __syncthreads();
    int segBase = b * MAXSEG, segLen = gcnt[b];
    for (int i = t; i < segLen; i += 1024)
        atomicAdd(&cntL[tmp[segBase + i] >> 16], 1);
    __syncthreads();
    if (t < 256) { padL[t] = (cntL[t] + 7) & ~7; scanL[t] = padL[t]; }
    __syncthreads();
    for (int off = 1; off < 256; off <<= 1) {
        int a = (t < 256) ? scanL[t] : 0;
        int s = (t >= off && t < 256) ? scanL[t - off] : 0;
        __syncthreads();
        if (t < 256) scanL[t] = a + s;
        __syncthreads();
    }
    if (t < 256) {
        int excl = scanL[t] - padL[t];
        curL[t] = excl;
        float dv = rsqrtf((float)cntL[t] + 1.0f);
        sdinv[t] = dv;
        int node = b * 256 + t;
        if (node < N) {
            row_start[node] = b * MAXSEG + excl;
            row_cntp[node]  = padL[t];
            dinv[node]      = dv;
        }
    }
    __syncthreads();
    for (int i = t; i < segLen; i += 1024) {
        unsigned e = tmp[segBase + i];
        int idx = atomicAdd(&curL[e >> 16], 1);
        staged[idx] = (u16)(e & 0xffffu);
    }
    for (int i = t; i < 256 * 16; i += 1024) {
        int nlc = i >> 4, cch = i & 15;
        int node = b * 256 + nlc;
        if (node < N)
            xp[(size_t)node * 16 + cch] =
                (cch < FEAT) ? f2bf(sdinv[nlc] * x[(size_t)node * FEAT + cch]) : (u16)0;
    }
    __syncthreads();
    ((uint4*)(csr2 + (size_t)b * MAXSEG))[t] = ((const uint4*)staged)[t];
}

// ================= fused layer1 (gather_x+mm1) + layer2-matmul (W2, MFMA) =============
// 256 threads, 64 nodes per block. h1 (bf16) never leaves LDS.

__global__ __launch_bounds__(256) void l1l2(
        const int* __restrict__ row_start, const int* __restrict__ row_cntp,
        const u16* __restrict__ csr2, const u16* __restrict__ xp,
        const float* __restrict__ dinv,
        const float* __restrict__ W1, const float* __restrict__ b1,
        const float* __restrict__ W2,
        u16* __restrict__ hwba, int N) {
    __shared__ float sW1[FEAT * 64];
    __shared__ float sH16[64 * 16];
    __shared__ __align__(16) u16 sHbf[64 * HSTR];   // h1 rows, bf16
    __shared__ __align__(16) u16 sWT[64 * HSTR];    // W2^T, bf16: sWT[c][k]
    __shared__ float sdv[64];
    int t = threadIdx.x;
    int node0 = blockIdx.x * 64;
    for (int i = t; i < FEAT * 64; i += 256) sW1[i] = W1[i];
    for (int i = t; i < 4096; i += 256) {           // W2 -> transposed bf16
        int k = i >> 6, c = i & 63;
        sWT[c * HSTR + k] = f2bf(W2[i]);
    }
    if (t < 64) sdv[t] = (node0 + t < N) ? dinv[node0 + t] : 0.f;
    if (t < 128) {
        int nl = t >> 1;
        int node = node0 + nl;
        int c0 = (t & 1) * 8;
        float acc[8] = {0.f,0.f,0.f,0.f,0.f,0.f,0.f,0.f};
        if (node < N) {
            uint4 sv = *(const uint4*)(xp + (size_t)node * 16 + c0);
            bf8_add(acc, sv);
            gather_rows<16>(acc, xp, csr2, row_start[node], row_cntp[node], c0);
            float di = dinv[node];
            #pragma unroll
            for (int j = 0; j < 8; j++) acc[j] *= di;
        }
        #pragma unroll
        for (int j = 0; j < 8; j++) sH16[nl * 16 + c0 + j] = acc[j];
    }
    __syncthreads();
    // mm1: h1 = relu(agg @ W1 + b1) -> sHbf (bf16)
    int c0 = (t & 15) * 4;
    int rbase = (t >> 4) * 4;
    {
        float4 a0 = {0,0,0,0}, a1 = {0,0,0,0}, a2 = {0,0,0,0}, a3 = {0,0,0,0};
        for (int k = 0; k < FEAT; k++) {
            float4 w = *(const float4*)(sW1 + k * 64 + c0);
            float h0 = sH16[(rbase + 0) * 16 + k];
            float h1v = sH16[(rbase + 1) * 16 + k];
            float h2 = sH16[(rbase + 2) * 16 + k];
            float h3 = sH16[(rbase + 3) * 16 + k];
            a0.x += h0 * w.x; a0.y += h0 * w.y; a0.z += h0 * w.z; a0.w += h0 * w.w;
            a1.x += h1v * w.x; a1.y += h1v * w.y; a1.z += h1v * w.z; a1.w += h1v * w.w;
            a2.x += h2 * w.x; a2.y += h2 * w.y; a2.z += h2 * w.z; a2.w += h2 * w.w;
            a3.x += h3 * w.x; a3.y += h3 * w.y; a3.z += h3 * w.z; a3.w += h3 * w.w;
        }
        float4 bb = *(const float4*)(b1 + c0);
        float4 accs[4] = {a0, a1, a2, a3};
        #pragma unroll
        for (int rr = 0; rr < 4; rr++) {
            float4 v = accs[rr];
            int r = rbase + rr;
            ushort4 o;
            o.x = f2bf(fmaxf(v.x + bb.x, 0.f));
            o.y = f2bf(fmaxf(v.y + bb.y, 0.f));
            o.z = f2bf(fmaxf(v.z + bb.z, 0.f));
            o.w = f2bf(fmaxf(v.w + bb.w, 0.f));
            *(ushort4*)(sHbf + r * HSTR + c0) = o;
        }
    }
    __syncthreads();
    // MFMA: hwba = bf16(dinv * (h1 @ W2)). 4 waves x (16 rows x 64 cols).
    {
        int lane = t & 63, w = t >> 6;
        int cl = lane & 15, g = lane >> 4;
        f32x4 ac0 = {0,0,0,0}, ac1 = {0,0,0,0}, ac2 = {0,0,0,0}, ac3 = {0,0,0,0};
        const u16* arow = sHbf + (16 * w + cl) * HSTR;
        #pragma unroll
        for (int kh = 0; kh < 2; kh++) {
            bf16x8 a  = *(const bf16x8*)(arow + kh * 32 + g * 8);
            bf16x8 f0 = *(const bf16x8*)(sWT + (cl)      * HSTR + kh * 32 + g * 8);
            bf16x8 f1 = *(const bf16x8*)(sWT + (16 + cl) * HSTR + kh * 32 + g * 8);
            bf16x8 f2 = *(const bf16x8*)(sWT + (32 + cl) * HSTR + kh * 32 + g * 8);
            bf16x8 f3 = *(const bf16x8*)(sWT + (48 + cl) * HSTR + kh * 32 + g * 8);
            ac0 = __builtin_amdgcn_mfma_f32_16x16x32_bf16(a, f0, ac0, 0, 0, 0);
            ac1 = __builtin_amdgcn_mfma_f32_16x16x32_bf16(a, f1, ac1, 0, 0, 0);
            ac2 = __builtin_amdgcn_mfma_f32_16x16x32_bf16(a, f2, ac2, 0, 0, 0);
            ac3 = __builtin_amdgcn_mfma_f32_16x16x32_bf16(a, f3, ac3, 0, 0, 0);
        }
        int r0 = 16 * w + 4 * g;
        #pragma unroll
        for (int reg = 0; reg < 4; reg++) {
            int node = node0 + r0 + reg;
            if (node < N) {
                float dv = sdv[r0 + reg];
                hwba[(size_t)node * 64 +  0 + cl] = f2bf(ac0[reg] * dv);
                hwba[(size_t)node * 64 + 16 + cl] = f2bf(ac1[reg] * dv);
                hwba[(size_t)node * 64 + 32 + cl] = f2bf(ac2[reg] * dv);
                hwba[(size_t)node * 64 + 48 + cl] = f2bf(ac3[reg] * dv);
            }
        }
    }
}

// ================= fused layer2-gather (b2) + layer3-matmul (W3, MFMA) ================
// 512 threads, 64 nodes per block. h2 (bf16) never leaves LDS.

__global__ __launch_bounds__(512) void g2l3(
        const int* __restrict__ row_start, const int* __restrict__ row_cntp,
        const u16* __restrict__ csr2, const u16* __restrict__ hwba,
        const float* __restrict__ dinv, const float* __restrict__ b2,
        const float* __restrict__ W3,
        u16* __restrict__ hwbb, int N) {
    __shared__ __align__(16) u16 sHbf[64 * HSTR];   // h2 rows, bf16
    __shared__ __align__(16) u16 sWT[64 * HSTR];    // W3^T, bf16
    __shared__ float sdv[64];
    int t = threadIdx.x;
    int node0 = blockIdx.x * 64;
    {
        int nl = t >> 3;                 // 0..63 node slot
        int node = node0 + nl;
        int c0 = (t & 7) * 8;
        float acc[8] = {0.f,0.f,0.f,0.f,0.f,0.f,0.f,0.f};
        if (node < N) {
            uint4 sv = *(const uint4*)(hwba + (size_t)node * 64 + c0);
            bf8_add(acc, sv);
            gather_rows<64>(acc, hwba, csr2, row_start[node], row_cntp[node], c0);
            float di = dinv[node];
            const float4 bb0 = *(const float4*)(b2 + c0);
            const float4 bb1 = *(const float4*)(b2 + c0 + 4);
            acc[0] = fmaxf(acc[0]*di + bb0.x, 0.f); acc[1] = fmaxf(acc[1]*di + bb0.y, 0.f);
            acc[2] = fmaxf(acc[2]*di + bb0.z, 0.f); acc[3] = fmaxf(acc[3]*di + bb0.w, 0.f);
            acc[4] = fmaxf(acc[4]*di + bb1.x, 0.f); acc[5] = fmaxf(acc[5]*di + bb1.y, 0.f);
            acc[6] = fmaxf(acc[6]*di + bb1.z, 0.f); acc[7] = fmaxf(acc[7]*di + bb1.w, 0.f);
        }
        ushort4 lo, hi;
        lo.x = f2bf(acc[0]); lo.y = f2bf(acc[1]); lo.z = f2bf(acc[2]); lo.w = f2bf(acc[3]);
        hi.x = f2bf(acc[4]); hi.y = f2bf(acc[5]); hi.z = f2bf(acc[6]); hi.w = f2bf(acc[7]);
        *(ushort4*)(sHbf + nl * HSTR + c0)     = lo;
        *(ushort4*)(sHbf + nl * HSTR + c0 + 4) = hi;
    }
    for (int i = t; i < 4096; i += 512) {           // W3 -> transposed bf16
        int k = i >> 6, c = i & 63;
        sWT[c * HSTR + k] = f2bf(W3[i]);
    }
    if (t < 64) sdv[t] = (node0 + t < N) ? dinv[node0 + t] : 0.f;
    __syncthreads();
    // MFMA: hwbb = bf16(dinv * (h2 @ W3)). 8 waves x (16 rows x 32 cols).
    {
        int lane = t & 63, w = t >> 6;
        int cl = lane & 15, g = lane >> 4;
        int strip = w >> 1;              // row-tile 0..3
        int tb = (w & 1) * 2;            // first col-tile (0 or 2)
        f32x4 acA = {0,0,0,0}, acB = {0,0,0,0};
        const u16* arow = sHbf + (16 * strip + cl) * HSTR;
        #pragma unroll
        for (int kh = 0; kh < 2; kh++) {
            bf16x8 a  = *(const bf16x8*)(arow + kh * 32 + g * 8);
            bf16x8 fA = *(const bf16x8*)(sWT + (16 * tb       + cl) * HSTR + kh * 32 + g * 8);
            bf16x8 fB = *(const bf16x8*)(sWT + (16 * (tb + 1) + cl) * HSTR + kh * 32 + g * 8);
            acA = __builtin_amdgcn_mfma_f32_16x16x32_bf16(a, fA, acA, 0, 0, 0);
            acB = __builtin_amdgcn_mfma_f32_16x16x32_bf16(a, fB, acB, 0, 0, 0);
        }
        int r0 = 16 * strip + 4 * g;
        #pragma unroll
        for (int reg = 0; reg < 4; reg++) {
            int node = node0 + r0 + reg;
            if (node < N) {
                float dv = sdv[r0 + reg];
                hwbb[(size_t)node * 64 + 16 * tb       + cl] = f2bf(acA[reg] * dv);
                hwbb[(size_t)node * 64 + 16 * (tb + 1) + cl] = f2bf(acB[reg] * dv);
            }
        }
    }
}

// ================= layer3 gather (b3) -> h3 + per-block partial sums =================

__global__ __launch_bounds__(256) void gather_b3(
        const int* __restrict__ row_start, const int* __restrict__ row_cntp,
        const u16* __restrict__ csr2, const u16* __restrict__ hwbb,
        const float* __restrict__ dinv, const float* __restrict__ b,
        float* __restrict__ out, float* __restrict__ part, int N) {
    int t = threadIdx.x;
    int nl = t >> 3;
    int node = blockIdx.x * 32 + nl;
    int c0 = (t & 7) * 8;
    float acc[8] = {0.f,0.f,0.f,0.f,0.f,0.f,0.f,0.f};
    if (node < N) {
        uint4 sv = *(const uint4*)(hwbb + (size_t)node * 64 + c0);
        bf8_add(acc, sv);
        gather_rows<64>(acc, hwbb, csr2, row_start[node], row_cntp[node], c0);
        float di = dinv[node];
        const float4 bb0 = *(const float4*)(b + c0);
        const float4 bb1 = *(const float4*)(b + c0 + 4);
        float4 o0, o1;
        o0.x = fmaxf(acc[0]*di + bb0.x, 0.f); o0.y = fmaxf(acc[1]*di + bb0.y, 0.f);
        o0.z = fmaxf(acc[2]*di + bb0.z, 0.f); o0.w = fmaxf(acc[3]*di + bb0.w, 0.f);
        o1.x = fmaxf(acc[4]*di + bb1.x, 0.f); o1.y = fmaxf(acc[5]*di + bb1.y, 0.f);
        o1.z = fmaxf(acc[6]*di + bb1.z, 0.f); o1.w = fmaxf(acc[7]*di + bb1.w, 0.f);
        *(float4*)(out + (size_t)node * 64 + c0)     = o0;
        *(float4*)(out + (size_t)node * 64 + c0 + 4) = o1;
        acc[0]=o0.x; acc[1]=o0.y; acc[2]=o0.z; acc[3]=o0.w;
        acc[4]=o1.x; acc[5]=o1.y; acc[6]=o1.z; acc[7]=o1.w;
    }
    __shared__ float red[32 * 64];
    #pragma unroll
    for (int j = 0; j < 8; j++) red[nl * 64 + c0 + j] = acc[j];
    __syncthreads();
    if (t < 64) {
        float s = 0.f;
        #pragma unroll 8
        for (int k = 0; k < 32; k++) s += red[k * 64 + t];
        part[(size_t)blockIdx.x * 64 + t] = s;
    }
}

__global__ __launch_bounds__(64) void gsum_reduce(const float* __restrict__ part,
                                                  float* __restrict__ gsum, int NB) {
    int c = blockIdx.x, t = threadIdx.x;
    float s = 0.f;
    for (int i = t; i < NB; i += 64) s += part[(size_t)i * 64 + c];
    for (int off = 32; off > 0; off >>= 1) s += __shfl_down(s, off, 64);
    if (t == 0) gsum[c] = s;
}

// ================= head =================

__global__ __launch_bounds__(256) void final_kernel(
        const float* __restrict__ h3, const int* __restrict__ sheet_idx,
        const float* __restrict__ sheet_feat, const float* __restrict__ g_sum,
        const float* __restrict__ gW1, const float* __restrict__ gb1,
        const float* __restrict__ gW2, const float* __restrict__ gb2,
        const float* __restrict__ fW,  const float* __restrict__ fb,
        const float* __restrict__ qW1, const float* __restrict__ qb1,
        const float* __restrict__ qW2, const float* __restrict__ qb2,
        float* __restrict__ out, int N, int L) {
    int s = blockIdx.x, t = threadIdx.x;
    __shared__ float red[256];
    __shared__ float semb[64];
    __shared__ float geoh[64];
    __shared__ float geo[64];
    __shared__ float hq[128];
    int c = t & 63, jg = t >> 6;
    float acc = 0.0f;
    for (int j = jg; j < L; j += 4) {
        int node = sheet_idx[s * L + j];
        acc += h3[(size_t)node * 64 + c];
    }
    red[t] = acc;
    __syncthreads();
    if (t < 64) {
        semb[t] = (red[t] + red[t + 64] + red[t + 128] + red[t + 192]) / (float)L;
        hq[64 + t] = g_sum[t] / (float)N;
        float a = gb1[t];
        #pragma unroll
        for (int k = 0; k < FEAT; k++) a += sheet_feat[s * FEAT + k] * gW1[k * 64 + t];
        geoh[t] = fmaxf(a, 0.0f);
    }
    __syncthreads();
    if (t < 64) {
        float a = gb2[t];
        for (int k = 0; k < 64; k++) a += geoh[k] * gW2[k * 64 + t];
        geo[t] = a;
    }
    __syncthreads();
    if (t < 64) {
        float a = fb[t];
        for (int k = 0; k < 64; k++) a += semb[k] * fW[k * 64 + t];
        for (int k = 0; k < 64; k++) a += geo[k]  * fW[(64 + k) * 64 + t];
        hq[t] = fmaxf(a, 0.0f);
    }
    __syncthreads();
    float q = 0.0f;
    if (t < 64) {
        float a = qb1[t];
        for (int k = 0; k < 128; k++) a += hq[k] * qW1[k * 64 + t];
        a = fmaxf(a, 0.0f);
        q = a * qW2[t];
        for (int off = 32; off > 0; off >>= 1) q += __shfl_down(q, off, 64);
        if (t == 0) out[s] = q + qb2[0];
    }
}

extern "C" void kernel_launch(void* const* d_in, const int* in_sizes, int n_in,
                              void* d_out, int out_size, void* d_ws, size_t ws_size,
                              hipStream_t stream) {
    const float* x          = (const float*)d_in[0];
    const int*   edge       = (const int*)d_in[1];
    const int*   sheet_idx  = (const int*)d_in[3];
    const float* sheet_feat = (const float*)d_in[4];
    const float* W1 = (const float*)d_in[5];  const float* b1 = (const float*)d_in[6];
    const float* W2 = (const float*)d_in[7];  const float* b2 = (const float*)d_in[8];
    const float* W3 = (const float*)d_in[9];  const float* b3 = (const float*)d_in[10];
    const float* gW1 = (const float*)d_in[11]; const float* gb1 = (const float*)d_in[12];
    const float* gW2 = (const float*)d_in[13]; const float* gb2 = (const float*)d_in[14];
    const float* fW  = (const float*)d_in[15]; const float* fb  = (const float*)d_in[16];
    const float* qW1 = (const float*)d_in[17]; const float* qb1 = (const float*)d_in[18];
    const float* qW2 = (const float*)d_in[19]; const float* qb2 = (const float*)d_in[20];
    float* out = (float*)d_out;

    int N = in_sizes[2];            // 50000
    int E = in_sizes[1] / 2;        // 800000
    int S = in_sizes[4] / FEAT;     // 256
    int L = in_sizes[3] / S;        // 128

    int nbuckets = (N + 255) / 256;     // 196 (u16 src requires N < 65535)
    int nchunks  = (E + 4095) / 4096;   // 196

    int gMM = (N + 63) / 64;            // 782
    int gGB = (N + 31) / 32;            // 1563

    char* p = (char*)d_ws;
    unsigned* tmp  = (unsigned*)p;             p += (size_t)nbuckets * MAXSEG * 4;
    u16* csr2      = (u16*)p;                  p += (size_t)nbuckets * MAXSEG * 2;
    float* hf      = (float*)p;                p += (size_t)N * 64 * 4;       // h3 only
    u16* hwba      = (u16*)p;                  p += (size_t)(N + 1) * 64 * 2; // layer2 matmul out
    u16* hwbb      = (u16*)p;                  p += (size_t)(N + 1) * 64 * 2; // layer3 matmul out
    u16* xp        = (u16*)p;                  p += (size_t)(N + 1) * 16 * 2;
    int* row_start = (int*)p;                  p += (size_t)N * 4;
    int* row_cntp  = (int*)p;                  p += (size_t)N * 4;
    float* dinv    = (float*)p;                p += (size_t)N * 4;
    float* part    = (float*)p;                p += (size_t)gGB * 64 * 4;     // block partials
    int* gcnt      = (int*)p;                  p += 256 * 4;
    float* gsum    = (float*)p;                p += 64 * 4;

    hipMemsetAsync(gcnt, 0, 256 * 4, stream);

    const int* src = edge;
    const int* dst = edge + E;

    bin_kernel<<<nchunks, 1024, 0, stream>>>(src, dst, gcnt, tmp, hwba, hwbb, xp, E, N);
    csr_build<<<nbuckets, 1024, 0, stream>>>(tmp, gcnt, csr2, row_start, row_cntp, dinv, x, xp, N);

    l1l2<<<gMM, 256, 0, stream>>>(row_start, row_cntp, csr2, xp, dinv, W1, b1, W2, hwba, N);
    g2l3<<<gMM, 512, 0, stream>>>(row_start, row_cntp, csr2, hwba, dinv, b2, W3, hwbb, N);
    gather_b3<<<gGB, 256, 0, stream>>>(row_start, row_cntp, csr2, hwbb, dinv, b3, hf, part, N);
    gsum_reduce<<<64, 64, 0, stream>>>(part, gsum, gGB);

    final_kernel<<<S, 256, 0, stream>>>(hf, sheet_idx, sheet_feat, gsum,
                                        gW1, gb1, gW2, gb2, fW, fb,
                                        qW1, qb1, qW2, qb2, out, N, L);
}